// Round 4
// baseline (386.475 us; speedup 1.0000x reference)
//
#include <hip/hip_runtime.h>
#include <hip/hip_cooperative_groups.h>
#include <hip/hip_bf16.h>
#include <math.h>

namespace cg = cooperative_groups;

#define NBOX  540      // total boxes per batch
#define NOBJ  135      // unique objects per batch
#define ZW    64
#define HIDN  512
#define NOUT  12288    // 3*64*64
#define OBJS  64
#define BATCH 4
#define MROWS 540      // BATCH*NOBJ decode rows
#define MPAD  640      // padded decode rows (5 x 128 tiles)
#define GRID  480      // cooperative grid (= gemm2 tile count 96*5)
#define CVTJOBS ((NOUT / 64) * (HIDN / 64))   // 1536

// workspace layout (bytes), all 256-aligned
#define OFF_N      0u
#define OFF_PARAMS 256u         // float4 * 4*540 = 34560
#define OFF_OBJS   34816u       // int * 4*540 = 8640
#define OFF_HBF    43520u       // ushort * 640*512 = 655360
#define OFF_W2T    698880u      // ushort * 12288*512 = 12582912
#define OFF_DEC    13281792u    // float * 540*12288 = 26542080  (total ~38 MB)

typedef short  bf16x8 __attribute__((ext_vector_type(8)));
typedef float  f32x4  __attribute__((ext_vector_type(4)));

#define GLOAD_LDS16(gp, lp)                                                    \
  __builtin_amdgcn_global_load_lds(                                            \
      (const __attribute__((address_space(1))) void*)(gp),                     \
      (__attribute__((address_space(3))) void*)(lp), 16, 0, 0)

__device__ __forceinline__ unsigned short f2bf(float x) {
  __hip_bfloat16 h = __float2bfloat16(x);
  return *(unsigned short*)&h;
}

// ---------------------------------------------------------------------------
// Single cooperative kernel: {sort+compact | gemm1 | W2 cvtT} -> sync ->
// gemm2 (bf16 MFMA) -> sync -> painter composite.
// ---------------------------------------------------------------------------
__global__ __launch_bounds__(256, 2) void k_fused(
    const float* __restrict__ z_depth,   // B*135
    const float* __restrict__ z_where,   // B*540*4
    const int*   __restrict__ z_present, // B*540
    const float* __restrict__ Z,         // B*135*64
    const float* __restrict__ W1,        // 64*512
    const float* __restrict__ b1,        // 512
    const float* __restrict__ W2,        // 512*12288
    const float* __restrict__ b2,        // 12288
    float4* __restrict__ params,
    int*    __restrict__ objs,
    int*    __restrict__ n_present,
    unsigned short* __restrict__ Hbf,    // 640*512 bf16
    unsigned short* __restrict__ W2T,    // 12288*512 bf16
    float* __restrict__ dec,             // 540*12288 f32
    float* __restrict__ out)             // 4*3*128*128
{
  __shared__ __align__(16) unsigned char lds_raw[16384];
  __shared__ int wsums[4], woff[4];
  const int bid = blockIdx.x;
  const int t   = threadIdx.x;
  cg::grid_group grid = cg::this_grid();

  // ======================= PHASE A: pre-work ===============================
  // A1: gemm1 rows (each block 1-2 rows)
  {
    float* zs = (float*)lds_raw;
    for (int r = bid; r < MPAD; r += GRID) {
      if (r >= MROWS) {
        Hbf[(size_t)r * HIDN + t] = 0;
        Hbf[(size_t)r * HIDN + t + 256] = 0;
      } else {
        __syncthreads();
        if (t < ZW) zs[t] = Z[(size_t)r * ZW + t];
        __syncthreads();
        float a0 = b1[t], a1 = b1[t + 256];
#pragma unroll 8
        for (int k = 0; k < ZW; k++) {
          float z = zs[k];
          a0 += z * W1[(size_t)k * HIDN + t];
          a1 += z * W1[(size_t)k * HIDN + t + 256];
        }
        Hbf[(size_t)r * HIDN + t]       = f2bf(fmaxf(a0, 0.f));
        Hbf[(size_t)r * HIDN + t + 256] = f2bf(fmaxf(a1, 0.f));
      }
    }
  }
  // A2: W2 (512 x 12288 f32) -> W2T (12288 x 512 bf16), 3-4 tiles per block
  {
    unsigned int* T = (unsigned int*)lds_raw;   // [64][36]
    for (int j = bid; j < CVTJOBS; j += GRID) {
      __syncthreads();
      const int n0 = (j % (NOUT / 64)) * 64;
      const int k0 = (j / (NOUT / 64)) * 64;
#pragma unroll
      for (int p = 0; p < 2; p++) {
        int kp = p * 16 + (t >> 4);
        int n4 = t & 15;
        int k  = k0 + kp * 2;
        float4 a = *(const float4*)&W2[(size_t)k * NOUT + n0 + n4 * 4];
        float4 b = *(const float4*)&W2[(size_t)(k + 1) * NOUT + n0 + n4 * 4];
        T[(n4*4 + 0) * 36 + kp] = (unsigned)f2bf(a.x) | ((unsigned)f2bf(b.x) << 16);
        T[(n4*4 + 1) * 36 + kp] = (unsigned)f2bf(a.y) | ((unsigned)f2bf(b.y) << 16);
        T[(n4*4 + 2) * 36 + kp] = (unsigned)f2bf(a.z) | ((unsigned)f2bf(b.z) << 16);
        T[(n4*4 + 3) * 36 + kp] = (unsigned)f2bf(a.w) | ((unsigned)f2bf(b.w) << 16);
      }
      __syncthreads();
#pragma unroll
      for (int p = 0; p < 2; p++) {
        int cc = p * 256 + t;
        int n = cc >> 3, ch = cc & 7;
        uint4 v = *(const uint4*)&T[n * 36 + ch * 4];
        *(uint4*)&W2T[(size_t)(n0 + n) * HIDN + k0 + ch * 8] = v;
      }
    }
  }
  // A3: sort 135 objects by depth desc (stable) + expand/compact (last 4 blocks)
  if (bid >= GRID - 4) {
    const int b = bid - (GRID - 4);
    unsigned long long* keys = (unsigned long long*)lds_raw;
    __syncthreads();
    unsigned long long key = ~0ull;
    if (t < NOBJ) {
      unsigned u = __float_as_uint(z_depth[b * NOBJ + t]);
      u = (u & 0x80000000u) ? ~u : (u | 0x80000000u);      // orderable uint
      key = ((unsigned long long)(~u) << 32) | (unsigned)t; // asc == depth desc, tie obj asc
    }
    keys[t] = key;
    __syncthreads();
    for (int k = 2; k <= 256; k <<= 1) {
      for (int j = k >> 1; j > 0; j >>= 1) {
        int ixj = t ^ j;
        if (ixj > t) {
          unsigned long long a = keys[t], c = keys[ixj];
          bool asc = (t & k) == 0;
          if (asc ? (a > c) : (a < c)) { keys[t] = c; keys[ixj] = a; }
        }
        __syncthreads();
      }
    }
    int boxq[3]; int presq[3]; int cnt = 0;
#pragma unroll
    for (int q = 0; q < 3; q++) {
      int e = 3 * t + q;
      presq[q] = 0; boxq[q] = 0;
      if (e < NBOX) {
        int o  = (int)(keys[e >> 2] & 0xFFFFFFFFull);
        int bx = o * 4 + (e & 3);
        boxq[q]  = bx;
        presq[q] = (z_present[b * NBOX + bx] != 0) ? 1 : 0;
        cnt += presq[q];
      }
    }
    int lane = t & 63, wv = t >> 6;
    int incl = cnt;
#pragma unroll
    for (int o = 1; o < 64; o <<= 1) {
      int vprev = __shfl_up(incl, o, 64);
      if (lane >= o) incl += vprev;
    }
    if (lane == 63) wsums[wv] = incl;
    __syncthreads();
    if (t == 0) {
      int a = 0;
#pragma unroll
      for (int i = 0; i < 4; i++) { woff[i] = a; a += wsums[i]; }
      n_present[b] = a;
    }
    __syncthreads();
    int slot = woff[wv] + incl - cnt;
#pragma unroll
    for (int q = 0; q < 3; q++) {
      if (presq[q]) {
        const float* zw = z_where + ((size_t)b * NBOX + boxq[q]) * 4;
        params[b * NBOX + slot] = make_float4(zw[0], zw[1], zw[2], zw[3]);
        objs[b * NBOX + slot]   = boxq[q] >> 2;
        slot++;
      }
    }
  }

  __threadfence();
  grid.sync();

  // ======================= PHASE B: gemm2 (bf16 MFMA) ======================
  {
    unsigned short* As = (unsigned short*)lds_raw;        // 128*32
    unsigned short* Bs = As + 128 * 32;                   // 128*32
    const int lane = t & 63, wv = t >> 6;
    const int n0 = (bid % (NOUT / 128)) * 128;
    const int m0 = (bid / (NOUT / 128)) * 128;
    const int wm = (wv & 1) * 64, wn = (wv >> 1) * 64;

    const int r0 = t >> 2;
    const int kc0 = (t & 3) ^ (r0 & 3);
    const int r1 = r0 + 64;
    const int kc1 = (t & 3) ^ (r1 & 3);

    const int fr = lane & 15;
    const int fj = lane >> 4;
    f32x4 acc[4][4] = {};

    for (int k0 = 0; k0 < HIDN; k0 += 32) {
      GLOAD_LDS16(Hbf + (size_t)(m0 + r0) * HIDN + k0 + kc0 * 8, &As[t * 8]);
      GLOAD_LDS16(Hbf + (size_t)(m0 + r1) * HIDN + k0 + kc1 * 8, &As[(t + 256) * 8]);
      GLOAD_LDS16(W2T + (size_t)(n0 + r0) * HIDN + k0 + kc0 * 8, &Bs[t * 8]);
      GLOAD_LDS16(W2T + (size_t)(n0 + r1) * HIDN + k0 + kc1 * 8, &Bs[(t + 256) * 8]);
      __syncthreads();

      bf16x8 av[4], bv[4];
#pragma unroll
      for (int mi = 0; mi < 4; mi++) {
        int row = wm + mi * 16 + fr;
        av[mi] = *(const bf16x8*)&As[(row * 4 + (fj ^ (row & 3))) * 8];
      }
#pragma unroll
      for (int ni = 0; ni < 4; ni++) {
        int row = wn + ni * 16 + fr;
        bv[ni] = *(const bf16x8*)&Bs[(row * 4 + (fj ^ (row & 3))) * 8];
      }
#pragma unroll
      for (int mi = 0; mi < 4; mi++)
#pragma unroll
        for (int ni = 0; ni < 4; ni++)
          acc[mi][ni] = __builtin_amdgcn_mfma_f32_16x16x32_bf16(av[mi], bv[ni], acc[mi][ni], 0, 0, 0);
      __syncthreads();
    }

#pragma unroll
    for (int ni = 0; ni < 4; ni++) {
      int col = n0 + wn + ni * 16 + fr;
      float bb = b2[col];
#pragma unroll
      for (int mi = 0; mi < 4; mi++) {
#pragma unroll
        for (int r = 0; r < 4; r++) {
          int row = m0 + wm + mi * 16 + fj * 4 + r;
          if (row < MROWS) {
            float v = acc[mi][ni][r] + bb;
            dec[(size_t)row * NOUT + col] = 1.0f / (1.0f + __expf(-v));
          }
        }
      }
    }
  }

  __threadfence();
  grid.sync();

  // ======================= PHASE C: painter composite ======================
  if (bid < 256) {
#pragma clang fp contract(off)
    float4* sp   = (float4*)lds_raw;               // 540*16 = 8640 B
    int*    sobj = (int*)(lds_raw + 8640);         // 540*4  = 2160 B
    const int b    = bid >> 6;
    const int tile = bid & 63;                     // 8x8 tiles of 16x16 px
    const int y = (tile >> 3) * 16 + (t >> 4);     // wave covers 16x4 region
    const int x = (tile & 7) * 16 + (t & 15);
    const int n = n_present[b];
    for (int i = t; i < n; i += 256) {
      sp[i]   = params[b * NBOX + i];
      sobj[i] = objs[b * NBOX + i];
    }
    __syncthreads();

    const double step = 2.0 / 127.0;
    const double gx = (x == 127) ? 1.0 : ((double)x * step + (-1.0));
    const double gy = (y == 127) ? 1.0 : ((double)y * step + (-1.0));

    float o0 = 0.f, o1 = 0.f, o2 = 0.f;
    bool done = false;
    for (int j = 0; j < n; j++) {
      if (__all((int)done)) break;
      if (!done) {
        float4 p = sp[j];
        double w = fmax((double)p.z, 0.01);
        double h = fmax((double)p.w, 0.01);
        double tx = 2.0 * (double)p.x - 1.0;
        double ty = 2.0 * (double)p.y - 1.0;
        double u = (gx - tx) / w;
        double v = (gy - ty) / h;
        double px = (u + 1.0) * 0.5 * 63.0;
        double py = (v + 1.0) * 0.5 * 63.0;
        double fx = floor(px), fy = floor(py);
        double wx = px - fx, wy = py - fy;
        int x0 = (int)fx, y0 = (int)fy;
        int x1 = x0 + 1, y1 = y0 + 1;
        bool vx0 = (x0 >= 0) && (x0 < OBJS);
        bool vx1 = (x1 >= 0) && (x1 < OBJS);
        bool vy0 = (y0 >= 0) && (y0 < OBJS);
        bool vy1 = (y1 >= 0) && (y1 < OBJS);
        double w00 = (1.0 - wy) * (1.0 - wx);
        double w01 = (1.0 - wy) * wx;
        double w10 = wy * (1.0 - wx);
        double w11 = wy * wx;
        bool c00 = vy0 && vx0 && (w00 > 0.0);
        bool c01 = vy0 && vx1 && (w01 > 0.0);
        bool c10 = vy1 && vx0 && (w10 > 0.0);
        bool c11 = vy1 && vx1 && (w11 > 0.0);
        if (c00 | c01 | c10 | c11) {
          const float* g = dec + (size_t)(b * NOBJ + sobj[j]) * NOUT;
          double s0 = 0.0, s1 = 0.0, s2 = 0.0;
          if (c00) { int o = y0*64 + x0; s0 += g[o]*w00; s1 += g[4096+o]*w00; s2 += g[8192+o]*w00; }
          if (c01) { int o = y0*64 + x1; s0 += g[o]*w01; s1 += g[4096+o]*w01; s2 += g[8192+o]*w01; }
          if (c10) { int o = y1*64 + x0; s0 += g[o]*w10; s1 += g[4096+o]*w10; s2 += g[8192+o]*w10; }
          if (c11) { int o = y1*64 + x1; s0 += g[o]*w11; s1 += g[4096+o]*w11; s2 += g[8192+o]*w11; }
          o0 = (float)s0; o1 = (float)s1; o2 = (float)s2;
          done = true;
        }
      }
    }
    const int ob = b * 3 * 16384 + y * 128 + x;    // (B,3,128,128)
    out[ob]         = o0;
    out[ob + 16384] = o1;
    out[ob + 32768] = o2;
  }
}

// ---------------------------------------------------------------------------
extern "C" void kernel_launch(void* const* d_in, const int* in_sizes, int n_in,
                              void* d_out, int out_size, void* d_ws, size_t ws_size,
                              hipStream_t stream) {
  (void)in_sizes; (void)n_in; (void)out_size; (void)ws_size;
  const float* z_what    = (const float*)d_in[0];
  const float* z_where   = (const float*)d_in[1];
  const float* z_depth   = (const float*)d_in[2];
  const float* W1        = (const float*)d_in[3];
  const float* b1        = (const float*)d_in[4];
  const float* W2        = (const float*)d_in[5];
  const float* b2        = (const float*)d_in[6];
  const int*   z_present = (const int*)d_in[7];
  float* out = (float*)d_out;
  char* ws = (char*)d_ws;

  int*            n_present = (int*)(ws + OFF_N);
  float4*         params    = (float4*)(ws + OFF_PARAMS);
  int*            objs      = (int*)(ws + OFF_OBJS);
  unsigned short* Hbf       = (unsigned short*)(ws + OFF_HBF);
  unsigned short* W2T       = (unsigned short*)(ws + OFF_W2T);
  float*          dec       = (float*)(ws + OFF_DEC);

  void* args[] = {
    (void*)&z_depth, (void*)&z_where, (void*)&z_present, (void*)&z_what,
    (void*)&W1, (void*)&b1, (void*)&W2, (void*)&b2,
    (void*)&params, (void*)&objs, (void*)&n_present,
    (void*)&Hbf, (void*)&W2T, (void*)&dec, (void*)&out
  };
  hipLaunchCooperativeKernel((void*)k_fused, dim3(GRID), dim3(256), args, 0, stream);
}

// Round 5
// 139.961 us; speedup vs baseline: 2.7613x; 2.7613x over previous
//
#include <hip/hip_runtime.h>
#include <hip/hip_bf16.h>
#include <math.h>

#define NBOX  540      // total boxes per batch
#define NOBJ  135      // unique objects per batch
#define ZW    64
#define HIDN  512
#define NOUT  12288    // 3*64*64
#define OBJS  64
#define BATCH 4
#define MROWS 540      // BATCH*NOBJ decode rows
#define MPAD  640      // padded decode rows (5 x 128 tiles)

// fused pre-kernel block roles
#define PRE_SORT   4
#define PRE_GEMM1  MPAD                    // 640
#define PRE_CVT    ((NOUT / 64) * (HIDN / 64))   // 1536
#define PRE_BLOCKS (PRE_SORT + PRE_GEMM1 + PRE_CVT)

// workspace layout (bytes), all 256-aligned
#define OFF_N      0u
#define OFF_PARAMS 256u         // float4 * 4*540 = 34560
#define OFF_OBJS   34816u       // int * 4*540 = 8640
#define OFF_HBF    43520u       // ushort * 640*512 = 655360
#define OFF_W2T    698880u      // ushort * 12288*512 = 12582912
#define OFF_DEC    13281792u    // float * 540*12288 = 26542080  (total ~38 MB)

typedef short  bf16x8 __attribute__((ext_vector_type(8)));
typedef float  f32x4  __attribute__((ext_vector_type(4)));

#define GLOAD_LDS16(gp, lp)                                                    \
  __builtin_amdgcn_global_load_lds(                                            \
      (const __attribute__((address_space(1))) void*)(gp),                     \
      (__attribute__((address_space(3))) void*)(lp), 16, 0, 0)

__device__ __forceinline__ unsigned short f2bf(float x) {
  __hip_bfloat16 h = __float2bfloat16(x);
  return *(unsigned short*)&h;
}

// ---------------------------------------------------------------------------
// K_pre: fused {per-batch object sort + box compaction | gemm1 | W2 cvt+T}
// ---------------------------------------------------------------------------
__global__ __launch_bounds__(256) void k_pre(
    const float* __restrict__ z_depth,   // B*135
    const float* __restrict__ z_where,   // B*540*4
    const int*   __restrict__ z_present, // B*540
    const float* __restrict__ Z,         // B*135*64 z_what
    const float* __restrict__ W1,        // 64*512
    const float* __restrict__ b1,        // 512
    const float* __restrict__ W2,        // 512*12288
    float4* __restrict__ params,         // B*540 (compacted, sorted)
    int*    __restrict__ objs,           // B*540
    int*    __restrict__ n_present,      // B
    unsigned short* __restrict__ Hbf,    // 640*512 bf16
    unsigned short* __restrict__ W2T)    // 12288*512 bf16
{
  __shared__ unsigned long long keys[256];   // sort role
  __shared__ int wsums[4], woff[4];
  __shared__ float zs[ZW];                   // gemm1 role
  __shared__ unsigned int T[64 * 36];        // cvt role

  const int bid = blockIdx.x;
  const int t   = threadIdx.x;

  if (bid < PRE_SORT) {
    // ---- role 0: sort 135 objects by depth desc (stable), expand+compact ----
    const int b = bid;
    unsigned long long key = ~0ull;
    if (t < NOBJ) {
      unsigned u = __float_as_uint(z_depth[b * NOBJ + t]);
      u = (u & 0x80000000u) ? ~u : (u | 0x80000000u);     // orderable uint
      key = ((unsigned long long)(~u) << 32) | (unsigned)t; // asc == depth desc, tie obj asc
    }
    keys[t] = key;
    __syncthreads();
    for (int k = 2; k <= 256; k <<= 1) {
      for (int j = k >> 1; j > 0; j >>= 1) {
        int ixj = t ^ j;
        if (ixj > t) {
          unsigned long long a = keys[t], c = keys[ixj];
          bool asc = (t & k) == 0;
          if (asc ? (a > c) : (a < c)) { keys[t] = c; keys[ixj] = a; }
        }
        __syncthreads();
      }
    }
    int boxq[3]; int presq[3]; int cnt = 0;
#pragma unroll
    for (int q = 0; q < 3; q++) {
      int e = 3 * t + q;
      presq[q] = 0; boxq[q] = 0;
      if (e < NBOX) {
        int o  = (int)(keys[e >> 2] & 0xFFFFFFFFull);
        int bx = o * 4 + (e & 3);
        boxq[q]  = bx;
        presq[q] = (z_present[b * NBOX + bx] != 0) ? 1 : 0;
        cnt += presq[q];
      }
    }
    int lane = t & 63, wv = t >> 6;
    int incl = cnt;
#pragma unroll
    for (int o = 1; o < 64; o <<= 1) {
      int vprev = __shfl_up(incl, o, 64);
      if (lane >= o) incl += vprev;
    }
    if (lane == 63) wsums[wv] = incl;
    __syncthreads();
    if (t == 0) {
      int a = 0;
#pragma unroll
      for (int i = 0; i < 4; i++) { woff[i] = a; a += wsums[i]; }
      n_present[b] = a;
    }
    __syncthreads();
    int slot = woff[wv] + incl - cnt;
#pragma unroll
    for (int q = 0; q < 3; q++) {
      if (presq[q]) {
        const float* zw = z_where + ((size_t)b * NBOX + boxq[q]) * 4;
        params[b * NBOX + slot] = make_float4(zw[0], zw[1], zw[2], zw[3]);
        objs[b * NBOX + slot]   = boxq[q] >> 2;
        slot++;
      }
    }
  } else if (bid < PRE_SORT + PRE_GEMM1) {
    // ---- role 1: H[r] = relu(Z[r] @ W1 + b1) -> bf16 (rows >=540 zeroed) ----
    const int r = bid - PRE_SORT;
    if (r >= MROWS) {
      Hbf[(size_t)r * HIDN + t] = 0;
      Hbf[(size_t)r * HIDN + t + 256] = 0;
      return;
    }
    if (t < ZW) zs[t] = Z[(size_t)r * ZW + t];
    __syncthreads();
    float a0 = b1[t], a1 = b1[t + 256];
#pragma unroll 8
    for (int k = 0; k < ZW; k++) {
      float z = zs[k];
      a0 += z * W1[(size_t)k * HIDN + t];
      a1 += z * W1[(size_t)k * HIDN + t + 256];
    }
    Hbf[(size_t)r * HIDN + t]       = f2bf(fmaxf(a0, 0.f));
    Hbf[(size_t)r * HIDN + t + 256] = f2bf(fmaxf(a1, 0.f));
  } else {
    // ---- role 2: W2 (512 x 12288 f32) -> W2T (12288 x 512 bf16) ----
    const int c  = bid - PRE_SORT - PRE_GEMM1;
    const int n0 = (c % (NOUT / 64)) * 64;
    const int k0 = (c / (NOUT / 64)) * 64;
#pragma unroll
    for (int p = 0; p < 2; p++) {
      int kp = p * 16 + (t >> 4);        // k-pair 0..31
      int n4 = t & 15;
      int k  = k0 + kp * 2;
      float4 a = *(const float4*)&W2[(size_t)k * NOUT + n0 + n4 * 4];
      float4 b = *(const float4*)&W2[(size_t)(k + 1) * NOUT + n0 + n4 * 4];
      T[(n4*4 + 0) * 36 + kp] = (unsigned)f2bf(a.x) | ((unsigned)f2bf(b.x) << 16);
      T[(n4*4 + 1) * 36 + kp] = (unsigned)f2bf(a.y) | ((unsigned)f2bf(b.y) << 16);
      T[(n4*4 + 2) * 36 + kp] = (unsigned)f2bf(a.z) | ((unsigned)f2bf(b.z) << 16);
      T[(n4*4 + 3) * 36 + kp] = (unsigned)f2bf(a.w) | ((unsigned)f2bf(b.w) << 16);
    }
    __syncthreads();
#pragma unroll
    for (int p = 0; p < 2; p++) {
      int cc = p * 256 + t;
      int n = cc >> 3, ch = cc & 7;      // 8 chunks of 8 k (16B)
      uint4 v = *(const uint4*)&T[n * 36 + ch * 4];
      *(uint4*)&W2T[(size_t)(n0 + n) * HIDN + k0 + ch * 8] = v;
    }
  }
}

// ---------------------------------------------------------------------------
// K2: dec = sigmoid(Hbf @ W2T^T + b2), bf16 MFMA 16x16x32, 128x128 tiles
// ---------------------------------------------------------------------------
__global__ __launch_bounds__(256) void k_gemm2_mfma(
    const unsigned short* __restrict__ Hbf,   // 640 x 512 bf16
    const unsigned short* __restrict__ W2T,   // 12288 x 512 bf16
    const float* __restrict__ b2,
    float* __restrict__ dec)                  // 540 x 12288 f32
{
  __shared__ unsigned short As[128 * 32];
  __shared__ unsigned short Bs[128 * 32];
  const int t    = threadIdx.x;
  const int lane = t & 63, wv = t >> 6;
  const int n0 = blockIdx.x * 128;
  const int m0 = blockIdx.y * 128;
  const int wm = (wv & 1) * 64, wn = (wv >> 1) * 64;

  const int r0 = t >> 2;
  const int kc0 = (t & 3) ^ (r0 & 3);
  const int r1 = r0 + 64;
  const int kc1 = (t & 3) ^ (r1 & 3);

  const int fr = lane & 15;
  const int fj = lane >> 4;
  f32x4 acc[4][4] = {};

  for (int k0 = 0; k0 < HIDN; k0 += 32) {
    GLOAD_LDS16(Hbf + (size_t)(m0 + r0) * HIDN + k0 + kc0 * 8, &As[t * 8]);
    GLOAD_LDS16(Hbf + (size_t)(m0 + r1) * HIDN + k0 + kc1 * 8, &As[(t + 256) * 8]);
    GLOAD_LDS16(W2T + (size_t)(n0 + r0) * HIDN + k0 + kc0 * 8, &Bs[t * 8]);
    GLOAD_LDS16(W2T + (size_t)(n0 + r1) * HIDN + k0 + kc1 * 8, &Bs[(t + 256) * 8]);
    __syncthreads();

    bf16x8 av[4], bv[4];
#pragma unroll
    for (int mi = 0; mi < 4; mi++) {
      int row = wm + mi * 16 + fr;
      av[mi] = *(const bf16x8*)&As[(row * 4 + (fj ^ (row & 3))) * 8];
    }
#pragma unroll
    for (int ni = 0; ni < 4; ni++) {
      int row = wn + ni * 16 + fr;
      bv[ni] = *(const bf16x8*)&Bs[(row * 4 + (fj ^ (row & 3))) * 8];
    }
#pragma unroll
    for (int mi = 0; mi < 4; mi++)
#pragma unroll
      for (int ni = 0; ni < 4; ni++)
        acc[mi][ni] = __builtin_amdgcn_mfma_f32_16x16x32_bf16(av[mi], bv[ni], acc[mi][ni], 0, 0, 0);
    __syncthreads();
  }

#pragma unroll
  for (int ni = 0; ni < 4; ni++) {
    int col = n0 + wn + ni * 16 + fr;
    float bb = b2[col];
#pragma unroll
    for (int mi = 0; mi < 4; mi++) {
#pragma unroll
      for (int r = 0; r < 4; r++) {
        int row = m0 + wm + mi * 16 + fj * 4 + r;
        if (row < MROWS) {
          float v = acc[mi][ni][r] + bb;
          dec[(size_t)row * NOUT + col] = 1.0f / (1.0f + __expf(-v));
        }
      }
    }
  }
}

// ---------------------------------------------------------------------------
// K3: painter composite, fp64 STN math (predicate-exact vs numpy-f64 gold).
// Block = 16x16 pixel tile; each wave covers a compact 16x4 region so the
// early-exit fires as soon as one box covers that small region.
// ---------------------------------------------------------------------------
__global__ __launch_bounds__(256) void k_composite(
    const float4* __restrict__ params, const int* __restrict__ objs,
    const int* __restrict__ n_present, const float* __restrict__ dec,
    float* __restrict__ out)
{
#pragma clang fp contract(off)
  __shared__ float4 sp[NBOX];
  __shared__ int sobj[NBOX];
  const int bid  = blockIdx.x;
  const int t    = threadIdx.x;
  const int b    = bid >> 6;                     // 4 batches x 64 tiles
  const int tile = bid & 63;                     // 8x8 tiles of 16x16 px
  const int y = (tile >> 3) * 16 + (t >> 4);     // wave covers 16x4 region
  const int x = (tile & 7) * 16 + (t & 15);
  const int n = n_present[b];
  for (int i = t; i < n; i += 256) {
    sp[i]   = params[b * NBOX + i];
    sobj[i] = objs[b * NBOX + i];
  }
  __syncthreads();

  const double step = 2.0 / 127.0;
  const double gx = (x == 127) ? 1.0 : ((double)x * step + (-1.0));
  const double gy = (y == 127) ? 1.0 : ((double)y * step + (-1.0));

  float o0 = 0.f, o1 = 0.f, o2 = 0.f;
  bool done = false;
  for (int j = 0; j < n; j++) {
    if (__all((int)done)) break;
    if (!done) {
      float4 p = sp[j];
      double w = fmax((double)p.z, 0.01);
      double h = fmax((double)p.w, 0.01);
      double tx = 2.0 * (double)p.x - 1.0;
      double ty = 2.0 * (double)p.y - 1.0;
      double u = (gx - tx) / w;
      double v = (gy - ty) / h;
      double px = (u + 1.0) * 0.5 * 63.0;
      double py = (v + 1.0) * 0.5 * 63.0;
      double fx = floor(px), fy = floor(py);
      double wx = px - fx, wy = py - fy;
      int x0 = (int)fx, y0 = (int)fy;
      int x1 = x0 + 1, y1 = y0 + 1;
      bool vx0 = (x0 >= 0) && (x0 < OBJS);
      bool vx1 = (x1 >= 0) && (x1 < OBJS);
      bool vy0 = (y0 >= 0) && (y0 < OBJS);
      bool vy1 = (y1 >= 0) && (y1 < OBJS);
      double w00 = (1.0 - wy) * (1.0 - wx);
      double w01 = (1.0 - wy) * wx;
      double w10 = wy * (1.0 - wx);
      double w11 = wy * wx;
      bool c00 = vy0 && vx0 && (w00 > 0.0);
      bool c01 = vy0 && vx1 && (w01 > 0.0);
      bool c10 = vy1 && vx0 && (w10 > 0.0);
      bool c11 = vy1 && vx1 && (w11 > 0.0);
      if (c00 | c01 | c10 | c11) {
        const float* g = dec + (size_t)(b * NOBJ + sobj[j]) * NOUT;
        double s0 = 0.0, s1 = 0.0, s2 = 0.0;
        if (c00) { int o = y0*64 + x0; s0 += g[o]*w00; s1 += g[4096+o]*w00; s2 += g[8192+o]*w00; }
        if (c01) { int o = y0*64 + x1; s0 += g[o]*w01; s1 += g[4096+o]*w01; s2 += g[8192+o]*w01; }
        if (c10) { int o = y1*64 + x0; s0 += g[o]*w10; s1 += g[4096+o]*w10; s2 += g[8192+o]*w10; }
        if (c11) { int o = y1*64 + x1; s0 += g[o]*w11; s1 += g[4096+o]*w11; s2 += g[8192+o]*w11; }
        o0 = (float)s0; o1 = (float)s1; o2 = (float)s2;
        done = true;
      }
    }
  }
  const int ob = b * 3 * 16384 + y * 128 + x;    // (B,3,128,128)
  out[ob]         = o0;
  out[ob + 16384] = o1;
  out[ob + 32768] = o2;
}

// ---------------------------------------------------------------------------
extern "C" void kernel_launch(void* const* d_in, const int* in_sizes, int n_in,
                              void* d_out, int out_size, void* d_ws, size_t ws_size,
                              hipStream_t stream) {
  (void)in_sizes; (void)n_in; (void)out_size; (void)ws_size;
  const float* z_what    = (const float*)d_in[0];
  const float* z_where   = (const float*)d_in[1];
  const float* z_depth   = (const float*)d_in[2];
  const float* W1        = (const float*)d_in[3];
  const float* b1        = (const float*)d_in[4];
  const float* W2        = (const float*)d_in[5];
  const float* b2        = (const float*)d_in[6];
  const int*   z_present = (const int*)d_in[7];
  float* out = (float*)d_out;
  char* ws = (char*)d_ws;

  int*            n_present = (int*)(ws + OFF_N);
  float4*         params    = (float4*)(ws + OFF_PARAMS);
  int*            objs      = (int*)(ws + OFF_OBJS);
  unsigned short* Hbf       = (unsigned short*)(ws + OFF_HBF);
  unsigned short* W2T       = (unsigned short*)(ws + OFF_W2T);
  float*          dec       = (float*)(ws + OFF_DEC);

  k_pre<<<dim3(PRE_BLOCKS), dim3(256), 0, stream>>>(
      z_depth, z_where, z_present, z_what, W1, b1, W2,
      params, objs, n_present, Hbf, W2T);
  k_gemm2_mfma<<<dim3(NOUT / 128, MPAD / 128), dim3(256), 0, stream>>>(Hbf, W2T, b2, dec);
  k_composite<<<dim3(256), dim3(256), 0, stream>>>(params, objs, n_present, dec, out);
}